// Round 2
// baseline (519.493 us; speedup 1.0000x reference)
//
#include <hip/hip_runtime.h>
#include <hip/hip_bf16.h>

#define NSIDE 128
#define NPIX (12 * NSIDE * NSIDE)   // 196608
#define BB 8
#define CIN 16
#define COUT 32
#define NROW (NPIX + 1)             // padded rows per batch

typedef _Float16 half8 __attribute__((ext_vector_type(8)));
typedef float floatx16 __attribute__((ext_vector_type(16)));

// Transpose + cast: x (B, CIN, NPIX) f32 -> xt (B, NPIX+1, CIN) f16.
// Each thread: 4 consecutive pixels x 16 channels via float4 loads,
// writes 4 rows x 32 B contiguous, nontemporal (xt = 50 MB, streams).
__global__ __launch_bounds__(256) void prep_xt(const float* __restrict__ x,
                                               _Float16* __restrict__ xt) {
    int t = blockIdx.x * 256 + threadIdx.x;           // [0, BB*NPIX/4)
    const int P4 = NPIX / 4;
    int b  = t / P4;
    int p4 = t - b * P4;
    const float* xb = x + (long)b * CIN * NPIX + p4 * 4;
    float4 ld[16];
#pragma unroll
    for (int c = 0; c < 16; c++)
        ld[c] = *(const float4*)(xb + (long)c * NPIX);
    _Float16* dst = xt + ((long)b * NROW + p4 * 4) * 16;
#pragma unroll
    for (int i = 0; i < 4; i++) {
        half8 lo, hi;
        lo[0]=(_Float16)(&ld[0].x)[i];  lo[1]=(_Float16)(&ld[1].x)[i];
        lo[2]=(_Float16)(&ld[2].x)[i];  lo[3]=(_Float16)(&ld[3].x)[i];
        lo[4]=(_Float16)(&ld[4].x)[i];  lo[5]=(_Float16)(&ld[5].x)[i];
        lo[6]=(_Float16)(&ld[6].x)[i];  lo[7]=(_Float16)(&ld[7].x)[i];
        hi[0]=(_Float16)(&ld[8].x)[i];  hi[1]=(_Float16)(&ld[9].x)[i];
        hi[2]=(_Float16)(&ld[10].x)[i]; hi[3]=(_Float16)(&ld[11].x)[i];
        hi[4]=(_Float16)(&ld[12].x)[i]; hi[5]=(_Float16)(&ld[13].x)[i];
        hi[6]=(_Float16)(&ld[14].x)[i]; hi[7]=(_Float16)(&ld[15].x)[i];
        __builtin_nontemporal_store(lo, (half8*)(dst + i * 16));
        __builtin_nontemporal_store(hi, (half8*)(dst + i * 16 + 8));
    }
}

// Weights (COUT, CIN, 9) f32 -> A-fragment layout wf[(k*64+lane)*8 + j] f16.
// Also zeroes the 8 pad rows of xt.
__global__ __launch_bounds__(256) void prep_wf(const float* __restrict__ w,
                                               _Float16* __restrict__ wf,
                                               _Float16* __restrict__ xt) {
    for (int e = threadIdx.x; e < 9 * 64 * 8; e += 256) {
        int k    = e >> 9;
        int lane = (e >> 3) & 63;
        int j    = e & 7;
        int o    = lane & 31;
        int c    = ((lane >> 5) << 3) + j;
        wf[e] = (_Float16)w[(o * CIN + c) * 9 + k];
    }
    int t = threadIdx.x;
    if (t < 128) {                 // 8 batches x 16 channels of the pad row
        int b = t >> 4, c = t & 15;
        xt[((long)b * NROW + NPIX) * 16 + c] = (_Float16)0.f;
    }
}

// One wave per 64-pixel tile-pair: two 32x32 MFMA accumulators, 18 gathers
// issued before first use. out stores nontemporal (don't evict gather set).
__global__ __launch_bounds__(256) void conv_main(const _Float16* __restrict__ xt,
                                                 const _Float16* __restrict__ wf,
                                                 const float* __restrict__ bias,
                                                 const int* __restrict__ nb,
                                                 float* __restrict__ out) {
    const int lane  = threadIdx.x & 63;
    const int wv    = threadIdx.x >> 6;
    const int pair  = blockIdx.x * 4 + wv;         // [0, BB*NPIX/64)
    const int PPB   = NPIX / 64;                   // pairs per batch
    const int b     = pair / PPB;
    const int p0    = (pair - b * PPB) * 64 + (lane & 31);
    const int p1    = p0 + 32;
    const int chalf = (lane >> 5) * 8;

    half8 wfrag[9];
#pragma unroll
    for (int k = 0; k < 9; k++)
        wfrag[k] = *(const half8*)(wf + ((k * 64 + lane) << 3));

    int idx0[9], idx1[9];
    const int* nbp0 = nb + p0 * 9;
    const int* nbp1 = nb + p1 * 9;
#pragma unroll
    for (int k = 0; k < 9; k++) idx0[k] = __builtin_nontemporal_load(nbp0 + k);
#pragma unroll
    for (int k = 0; k < 9; k++) idx1[k] = __builtin_nontemporal_load(nbp1 + k);

    const _Float16* xb = xt + (long)b * NROW * 16 + chalf;
    half8 v0[9], v1[9];
#pragma unroll
    for (int k = 0; k < 9; k++) v0[k] = *(const half8*)(xb + (long)idx0[k] * 16);
#pragma unroll
    for (int k = 0; k < 9; k++) v1[k] = *(const half8*)(xb + (long)idx1[k] * 16);

    floatx16 acc0, acc1;
#pragma unroll
    for (int i = 0; i < 16; i++) { acc0[i] = 0.f; acc1[i] = 0.f; }
#pragma unroll
    for (int k = 0; k < 9; k++) {
        acc0 = __builtin_amdgcn_mfma_f32_32x32x16_f16(wfrag[k], v0[k], acc0, 0, 0, 0);
        acc1 = __builtin_amdgcn_mfma_f32_32x32x16_f16(wfrag[k], v1[k], acc1, 0, 0, 0);
    }

    // C/D layout: col(pixel)=lane&31, row(o)=(r&3)+8*(r>>2)+4*(lane>>5)
    float* outb = out + (long)b * COUT * NPIX;
#pragma unroll
    for (int r = 0; r < 16; r++) {
        int o = (r & 3) + ((r >> 2) << 3) + ((lane >> 5) << 2);
        float bv = bias[o];
        __builtin_nontemporal_store(acc0[r] + bv, outb + (long)o * NPIX + p0);
        __builtin_nontemporal_store(acc1[r] + bv, outb + (long)o * NPIX + p1);
    }
}

extern "C" void kernel_launch(void* const* d_in, const int* in_sizes, int n_in,
                              void* d_out, int out_size, void* d_ws, size_t ws_size,
                              hipStream_t stream) {
    const float* x    = (const float*)d_in[0];
    const float* w    = (const float*)d_in[1];
    const float* bias = (const float*)d_in[2];
    const int*   nb   = (const int*)d_in[3];
    float*       out  = (float*)d_out;

    _Float16* wf = (_Float16*)d_ws;                      // 9216 B
    _Float16* xt = (_Float16*)((char*)d_ws + 16384);     // 50.3 MB

    hipLaunchKernelGGL(prep_xt, dim3(BB * NPIX / 4 / 256), dim3(256), 0, stream, x, xt);
    hipLaunchKernelGGL(prep_wf, dim3(1), dim3(256), 0, stream, w, wf, xt);
    hipLaunchKernelGGL(conv_main, dim3(BB * NPIX / 64 / 4), dim3(256), 0, stream,
                       xt, wf, bias, nb, out);
}